// Round 10
// baseline (629.441 us; speedup 1.0000x reference)
//
#include <hip/hip_runtime.h>
#include <math.h>

#define BSZ 1024
#define TS 7
#define DD 1024
#define HH 1024
#define NG 4096  // 4*H
#define NBLK 512 // persistent grid: 32 j-tiles x 16 row-tiles = 2 blocks/CU

typedef _Float16 f16x8 __attribute__((ext_vector_type(8)));
typedef _Float16 f16x4 __attribute__((ext_vector_type(4)));
typedef float f32x4 __attribute__((ext_vector_type(4)));

__device__ __forceinline__ float sigm_(float x) { return 1.f / (1.f + __expf(-x)); }
__device__ __forceinline__ float tanh_(float x) { return 1.f - 2.f / (__expf(2.f * x) + 1.f); }

__device__ __forceinline__ void gload16(const _Float16* g, _Float16* l) {
  __builtin_amdgcn_global_load_lds(
      (const __attribute__((address_space(1))) void*)g,
      (__attribute__((address_space(3))) void*)l, 16, 0, 0);
}

// Device-scope grid barrier (all NBLK blocks co-resident by construction).
__device__ __forceinline__ void grid_barrier(unsigned* c) {
  __threadfence();   // each thread's global writes visible device-wide
  __syncthreads();
  if (threadIdx.x == 0) {
    __hip_atomic_fetch_add(c, 1u, __ATOMIC_ACQ_REL, __HIP_MEMORY_SCOPE_AGENT);
    while (__hip_atomic_load(c, __ATOMIC_ACQUIRE, __HIP_MEMORY_SCOPE_AGENT) <
           (unsigned)NBLK) {
    }
  }
  __syncthreads();
}

// ---------------------------------------------------------------------------
// fp32 -> fp16 conversion for both weight matrices in one launch.
// ---------------------------------------------------------------------------
__global__ __launch_bounds__(256) void conv_w(const float* __restrict__ wih,
                                              const float* __restrict__ whh,
                                              _Float16* __restrict__ o_ih,
                                              _Float16* __restrict__ o_hh) {
  const int N4 = NG * DD / 4;  // per matrix
  for (int i = blockIdx.x * 256 + threadIdx.x; i < 2 * N4;
       i += gridDim.x * 256) {
    const float4 v = (i < N4) ? ((const float4*)wih)[i] : ((const float4*)whh)[i - N4];
    f16x4 o;
    o[0] = (_Float16)v.x; o[1] = (_Float16)v.y;
    o[2] = (_Float16)v.z; o[3] = (_Float16)v.w;
    if (i < N4) ((f16x4*)o_ih)[i] = o;
    else        ((f16x4*)o_hh)[i - N4] = o;
  }
}

// ---------------------------------------------------------------------------
// Kernel A: per-batch covariance stats. covT fp32 [B][TS]; covC fp16 [B][DD].
// ---------------------------------------------------------------------------
__global__ __launch_bounds__(256) void cov_kernel(
    const float* __restrict__ x, const float* __restrict__ xsh,
    float* __restrict__ covT, _Float16* __restrict__ covC16) {
  const int b = blockIdx.x, tid = threadIdx.x;
  const float4* xb = (const float4*)(x + (size_t)b * TS * DD);
  const float4* yb = (const float4*)(xsh + (size_t)b * TS * DD);
  float4 xv[TS], yv[TS];
#pragma unroll
  for (int t = 0; t < TS; t++) {
    xv[t] = xb[t * 256 + tid];
    yv[t] = yb[t * 256 + tid];
  }
  f16x4 cc;
#pragma unroll
  for (int q = 0; q < 4; q++) {
    float sx = 0.f, sy = 0.f, sxy = 0.f;
#pragma unroll
    for (int t = 0; t < TS; t++) {
      float a = ((const float*)&xv[t])[q];
      float c = ((const float*)&yv[t])[q];
      sx += a; sy += c; sxy += a * c;
    }
    float v = (sxy - sx * sy * (1.f / TS)) * (1.f / DD);
    cc[q] = (_Float16)(v > 0.f ? v : 0.f);
  }
  *(f16x4*)&covC16[(size_t)b * DD + tid * 4] = cc;

  float psx[TS], psy[TS], psxy[TS];
#pragma unroll
  for (int t = 0; t < TS; t++) {
    float4 a = xv[t], c = yv[t];
    psx[t] = a.x + a.y + a.z + a.w;
    psy[t] = c.x + c.y + c.z + c.w;
    psxy[t] = a.x * c.x + a.y * c.y + a.z * c.z + a.w * c.w;
  }
#pragma unroll
  for (int t = 0; t < TS; t++) {
    for (int m = 32; m >= 1; m >>= 1) {
      psx[t] += __shfl_xor(psx[t], m);
      psy[t] += __shfl_xor(psy[t], m);
      psxy[t] += __shfl_xor(psxy[t], m);
    }
  }
  __shared__ float red[3][4][TS];
  const int wave = tid >> 6, lane = tid & 63;
  if (lane == 0) {
#pragma unroll
    for (int t = 0; t < TS; t++) {
      red[0][wave][t] = psx[t];
      red[1][wave][t] = psy[t];
      red[2][wave][t] = psxy[t];
    }
  }
  __syncthreads();
  if (tid < TS) {
    float sx = red[0][0][tid] + red[0][1][tid] + red[0][2][tid] + red[0][3][tid];
    float sy = red[1][0][tid] + red[1][1][tid] + red[1][2][tid] + red[1][3][tid];
    float sxy = red[2][0][tid] + red[2][1][tid] + red[2][2][tid] + red[2][3][tid];
    float v = (sxy - sx * sy * (1.f / DD)) * (1.f / TS);
    covT[b * TS + tid] = v > 0.f ? v : 0.f;
  }
}

// ---------------------------------------------------------------------------
// Kernel B: PERSISTENT fused LSTM. One launch for all 7 timesteps, grid
// barrier between steps. Block owns (64 batch rows x 32 j) for all t, so
// M (x-gate preactivations) and c (cell state) live in REGISTERS.
// Tile 64 x 128 (4 gates x 32 j), BK=64, 4 waves; wave = row-quadrant,
// lane owns all 4 gates of 2 j-columns -> no cross-wave gate exchange.
// 2-phase prefetch; XOR-swizzled LDS via pre-swizzled global source.
// ---------------------------------------------------------------------------
__global__ __launch_bounds__(256, 2) void persist_lstm(
    const _Float16* __restrict__ covC16, const _Float16* __restrict__ Wih,
    const _Float16* __restrict__ Whh, const float* __restrict__ covT,
    const float* __restrict__ b_ih, const float* __restrict__ b_hh,
    _Float16* __restrict__ h16, unsigned* __restrict__ cnt) {
  __shared__ __align__(16) _Float16 As0[64 * 64];   // 8 KB
  __shared__ __align__(16) _Float16 Bs0[128 * 64];  // 16 KB
  __shared__ __align__(16) _Float16 As1[64 * 64];
  __shared__ __align__(16) _Float16 Bs1[128 * 64];  // total 48 KB

  const int tid = threadIdx.x;
  const int wave = tid >> 6, lane = tid & 63;
  const int l15 = lane & 15, lhi = lane >> 4;
  const int rowBase = blockIdx.y * 64;   // batch rows
  const int jBase = blockIdx.x * 32;     // hidden cols
  const int sRow = tid >> 3;             // 0..31 staging row
  const int sColSw = (((tid & 7) ^ (sRow & 7)) * 8);  // pre-swizzled k-chunk
  const int ldsOff = (tid & ~63) * 8;    // wave-uniform gload dest offset

  // hoisted bias: j = jBase + l15 + js*16, gate g
  float bia[4][2];
#pragma unroll
  for (int g = 0; g < 4; ++g)
#pragma unroll
    for (int js = 0; js < 2; ++js) {
      const int j = jBase + l15 + js * 16;
      bia[g][js] = b_ih[g * HH + j] + b_hh[g * HH + j];
    }

  f32x4 Mreg[8];       // x-gate preactivations, set at t=0 (nf = g*2+js)
  float cst[2][4];     // cell state per (js, r)

#define STAGE(as, bs, kt)                                                      \
  {                                                                            \
    const int k0 = (kt)*64;                                                    \
    gload16(&Ap[(size_t)(rowBase + sRow) * ldap + k0 + sColSw], (as) + ldsOff);\
    gload16(&Ap[(size_t)(rowBase + 32 + sRow) * ldap + k0 + sColSw],           \
            (as) + 2048 + ldsOff);                                             \
    gload16(&Wp[(size_t)(0 * HH + jBase + sRow) * DD + k0 + sColSw],           \
            (bs) + 0 + ldsOff);                                                \
    gload16(&Wp[(size_t)(1 * HH + jBase + sRow) * DD + k0 + sColSw],           \
            (bs) + 2048 + ldsOff);                                             \
    gload16(&Wp[(size_t)(2 * HH + jBase + sRow) * DD + k0 + sColSw],           \
            (bs) + 4096 + ldsOff);                                             \
    gload16(&Wp[(size_t)(3 * HH + jBase + sRow) * DD + k0 + sColSw],           \
            (bs) + 6144 + ldsOff);                                             \
  }

  // wave covers rows wave*16 + l15; lane's cols nf*16+l15 span all 4 gates
#define COMPUTE(as, bs)                                                        \
  {                                                                            \
    _Pragma("unroll") for (int kk = 0; kk < 2; ++kk) {                         \
      const int akx = (kk * 32 + lhi * 8) ^ ((l15 & 7) << 3);                  \
      const f16x8 af = *(const f16x8*)&(as)[(wave * 16 + l15) * 64 + akx];     \
      _Pragma("unroll") for (int nf = 0; nf < 8; ++nf) {                       \
        const f16x8 bf = *(const f16x8*)&(bs)[(nf * 16 + l15) * 64 + akx];     \
        acc[nf] = __builtin_amdgcn_mfma_f32_16x16x32_f16(af, bf, acc[nf],      \
                                                         0, 0, 0);             \
      }                                                                        \
    }                                                                          \
  }

#pragma unroll 1
  for (int t = 0; t < TS; ++t) {
    const _Float16* Ap = t ? h16 + (size_t)(t - 1) * HH : covC16;
    const int ldap = t ? TS * HH : DD;
    const _Float16* Wp = t ? Whh : Wih;
    f32x4 acc[8] = {};

    STAGE(As0, Bs0, 0);
    __syncthreads();
    for (int kt = 0; kt < 16; kt += 2) {
      STAGE(As1, Bs1, kt + 1);  // prefetch next, in flight during compute
      COMPUTE(As0, Bs0);
      __syncthreads();
      if (kt + 2 < 16) STAGE(As0, Bs0, kt + 2);
      COMPUTE(As1, Bs1);
      __syncthreads();
    }

    // ---- in-register epilogue: cell math, no LDS, no M/c global traffic ----
    float covt[4];
#pragma unroll
    for (int r = 0; r < 4; ++r)
      covt[r] = covT[(size_t)(rowBase + wave * 16 + lhi * 4 + r) * TS + t];
#pragma unroll
    for (int js = 0; js < 2; ++js)
#pragma unroll
      for (int r = 0; r < 4; ++r) {
        float pre[4];
#pragma unroll
        for (int g = 0; g < 4; ++g) {
          const int nf = g * 2 + js;
          if (t == 0) {
            Mreg[nf][r] = acc[nf][r];
            pre[g] = covt[r] * acc[nf][r] + bia[g][js];
          } else {
            pre[g] = acc[nf][r] + covt[r] * Mreg[nf][r] + bia[g][js];
          }
        }
        const float i_ = sigm_(pre[0]), f_ = sigm_(pre[1]);
        const float g_ = tanh_(pre[2]), o_ = sigm_(pre[3]);
        const float c_ = (t ? f_ * cst[js][r] : 0.f) + i_ * g_;
        cst[js][r] = c_;
        const size_t row = rowBase + wave * 16 + lhi * 4 + r;
        h16[row * TS * HH + (size_t)t * HH + jBase + l15 + js * 16] =
            (_Float16)(o_ * tanh_(c_));
      }

    if (t < TS - 1) grid_barrier(&cnt[t]);  // h(t) visible to all blocks
  }
#undef STAGE
#undef COMPUTE
}

// ---------------------------------------------------------------------------
// Kernel D: softmax over t + temporal attention, reading fp16 h_all.
// ---------------------------------------------------------------------------
__global__ __launch_bounds__(256) void finale(
    const _Float16* __restrict__ h16, const float* __restrict__ attn_W,
    const float* __restrict__ attn_b, float* __restrict__ out) {
  const int b = blockIdx.x, tid = threadIdx.x;
  const f16x4* hb = (const f16x4*)(h16 + (size_t)b * TS * HH);
  float v[TS][4];
#pragma unroll
  for (int t = 0; t < TS; t++) {
    f16x4 hv = hb[t * 256 + tid];
#pragma unroll
    for (int q = 0; q < 4; q++) v[t][q] = (float)hv[q];
  }
  const float4 aw = ((const float4*)attn_W)[tid];
  const float awa[4] = {aw.x, aw.y, aw.z, aw.w};

  float4 outv[TS];
#pragma unroll
  for (int q = 0; q < 4; q++) {
    float m = -1e30f;
#pragma unroll
    for (int t = 0; t < TS; t++) m = fmaxf(m, v[t][q]);
    float e[TS], s = 0.f;
#pragma unroll
    for (int t = 0; t < TS; t++) {
      e[t] = __expf(v[t][q] - m);
      s += e[t];
    }
    const float inv = 1.f / s;
#pragma unroll
    for (int t = 0; t < TS; t++) ((float*)&outv[t])[q] = e[t] * inv;
  }
#pragma unroll
  for (int t = 0; t < TS; t++)
    ((float4*)out)[(size_t)b * TS * 256 + t * 256 + tid] = outv[t];

  float pt[TS];
#pragma unroll
  for (int t = 0; t < TS; t++) {
    pt[t] = tanh_(v[t][0]) * awa[0] + tanh_(v[t][1]) * awa[1] +
            tanh_(v[t][2]) * awa[2] + tanh_(v[t][3]) * awa[3];
  }
#pragma unroll
  for (int t = 0; t < TS; t++)
    for (int m = 32; m >= 1; m >>= 1) pt[t] += __shfl_xor(pt[t], m);
  __shared__ float red[4][TS];
  const int wave = tid >> 6, lane = tid & 63;
  if (lane == 0) {
#pragma unroll
    for (int t = 0; t < TS; t++) red[wave][t] = pt[t];
  }
  __syncthreads();
  if (tid < TS) {
    float s = red[0][tid] + red[1][tid] + red[2][tid] + red[3][tid];
    out[(size_t)BSZ * TS * HH + b * TS + tid] = sigm_(s + attn_b[0]);
  }
}

// ---------------------------------------------------------------------------
extern "C" void kernel_launch(void* const* d_in, const int* in_sizes, int n_in,
                              void* d_out, int out_size, void* d_ws,
                              size_t ws_size, hipStream_t stream) {
  const float* x = (const float*)d_in[0];
  const float* xsh = (const float*)d_in[1];
  const float* W_ih = (const float*)d_in[2];
  const float* W_hh = (const float*)d_in[3];
  const float* b_ih = (const float*)d_in[4];
  const float* b_hh = (const float*)d_in[5];
  const float* attn_W = (const float*)d_in[6];
  const float* attn_b = (const float*)d_in[7];
  float* out = (float*)d_out;
  float* w = (float*)d_ws;

  // workspace (fp32 words), total ~33.6 MB
  unsigned* cnt = (unsigned*)w;                    // 16 words (6 used)
  float* covT = w + 16;                            // 7168 words
  _Float16* covC16 = (_Float16*)(w + 8192);        // 1M f16 (0.5M words)
  _Float16* Wih16 = (_Float16*)(w + 532480);       // 4M f16 (2M words)
  _Float16* Whh16 = (_Float16*)(w + 2629632);      // 4M f16 (2M words)
  _Float16* h16 = (_Float16*)(w + 4726784);        // 7M f16 (3.5M words)

  hipMemsetAsync(cnt, 0, 64, stream);  // zero barrier counters (ws is 0xAA)
  conv_w<<<1024, 256, 0, stream>>>(W_ih, W_hh, Wih16, Whh16);
  cov_kernel<<<dim3(BSZ), dim3(256), 0, stream>>>(x, xsh, covT, covC16);
  persist_lstm<<<dim3(32, 16), dim3(256), 0, stream>>>(
      covC16, Wih16, Whh16, covT, b_ih, b_hh, h16, cnt);
  finale<<<dim3(BSZ), dim3(256), 0, stream>>>(h16, attn_W, attn_b, out);
}

// Round 11
// 268.387 us; speedup vs baseline: 2.3453x; 2.3453x over previous
//
#include <hip/hip_runtime.h>
#include <math.h>

#define BSZ 1024
#define TS 7
#define DD 1024
#define HH 1024
#define NG 4096  // 4*H

typedef _Float16 f16x8 __attribute__((ext_vector_type(8)));
typedef _Float16 f16x4 __attribute__((ext_vector_type(4)));
typedef float f32x4 __attribute__((ext_vector_type(4)));
typedef float f32x16 __attribute__((ext_vector_type(16)));

__device__ __forceinline__ float sigm_(float x) { return 1.f / (1.f + __expf(-x)); }
__device__ __forceinline__ float tanh_(float x) { return 1.f - 2.f / (__expf(2.f * x) + 1.f); }

__device__ __forceinline__ void gload16(const _Float16* g, _Float16* l) {
  __builtin_amdgcn_global_load_lds(
      (const __attribute__((address_space(1))) void*)g,
      (__attribute__((address_space(3))) void*)l, 16, 0, 0);
}

// ---------------------------------------------------------------------------
// fp32 -> fp16 conversion for both weight matrices in one launch.
// ---------------------------------------------------------------------------
__global__ __launch_bounds__(256) void conv_w(const float* __restrict__ wih,
                                              const float* __restrict__ whh,
                                              _Float16* __restrict__ o_ih,
                                              _Float16* __restrict__ o_hh) {
  const int N4 = NG * DD / 4;  // per matrix
  for (int i = blockIdx.x * 256 + threadIdx.x; i < 2 * N4;
       i += gridDim.x * 256) {
    const float4 v = (i < N4) ? ((const float4*)wih)[i] : ((const float4*)whh)[i - N4];
    f16x4 o;
    o[0] = (_Float16)v.x; o[1] = (_Float16)v.y;
    o[2] = (_Float16)v.z; o[3] = (_Float16)v.w;
    if (i < N4) ((f16x4*)o_ih)[i] = o;
    else        ((f16x4*)o_hh)[i - N4] = o;
  }
}

// ---------------------------------------------------------------------------
// Kernel A: per-batch covariance stats. covT fp32 [B][TS]; covC fp16 [B][DD].
// ---------------------------------------------------------------------------
__global__ __launch_bounds__(256) void cov_kernel(
    const float* __restrict__ x, const float* __restrict__ xsh,
    float* __restrict__ covT, _Float16* __restrict__ covC16) {
  const int b = blockIdx.x, tid = threadIdx.x;
  const float4* xb = (const float4*)(x + (size_t)b * TS * DD);
  const float4* yb = (const float4*)(xsh + (size_t)b * TS * DD);
  float4 xv[TS], yv[TS];
#pragma unroll
  for (int t = 0; t < TS; t++) {
    xv[t] = xb[t * 256 + tid];
    yv[t] = yb[t * 256 + tid];
  }
  f16x4 cc;
#pragma unroll
  for (int q = 0; q < 4; q++) {
    float sx = 0.f, sy = 0.f, sxy = 0.f;
#pragma unroll
    for (int t = 0; t < TS; t++) {
      float a = ((const float*)&xv[t])[q];
      float c = ((const float*)&yv[t])[q];
      sx += a; sy += c; sxy += a * c;
    }
    float v = (sxy - sx * sy * (1.f / TS)) * (1.f / DD);
    cc[q] = (_Float16)(v > 0.f ? v : 0.f);
  }
  *(f16x4*)&covC16[(size_t)b * DD + tid * 4] = cc;

  float psx[TS], psy[TS], psxy[TS];
#pragma unroll
  for (int t = 0; t < TS; t++) {
    float4 a = xv[t], c = yv[t];
    psx[t] = a.x + a.y + a.z + a.w;
    psy[t] = c.x + c.y + c.z + c.w;
    psxy[t] = a.x * c.x + a.y * c.y + a.z * c.z + a.w * c.w;
  }
#pragma unroll
  for (int t = 0; t < TS; t++) {
    for (int m = 32; m >= 1; m >>= 1) {
      psx[t] += __shfl_xor(psx[t], m);
      psy[t] += __shfl_xor(psy[t], m);
      psxy[t] += __shfl_xor(psxy[t], m);
    }
  }
  __shared__ float red[3][4][TS];
  const int wave = tid >> 6, lane = tid & 63;
  if (lane == 0) {
#pragma unroll
    for (int t = 0; t < TS; t++) {
      red[0][wave][t] = psx[t];
      red[1][wave][t] = psy[t];
      red[2][wave][t] = psxy[t];
    }
  }
  __syncthreads();
  if (tid < TS) {
    float sx = red[0][0][tid] + red[0][1][tid] + red[0][2][tid] + red[0][3][tid];
    float sy = red[1][0][tid] + red[1][1][tid] + red[1][2][tid] + red[1][3][tid];
    float sxy = red[2][0][tid] + red[2][1][tid] + red[2][2][tid] + red[2][3][tid];
    float v = (sxy - sx * sy * (1.f / DD)) * (1.f / TS);
    covT[b * TS + tid] = v > 0.f ? v : 0.f;
  }
}

// ---------------------------------------------------------------------------
// Kernel B: fused GEMM + LSTM cell, one launch per timestep.
// 32x32x16 MFMA: wave (=gate) computes 64 rows x 32 cols as 2 MFMA tiles.
// Per k-16 step: 2 A reads + 1 B read -> 2 MFMA (was 9 reads / 8 MFMA with
// 16x16x32): 72 -> 48 ds_read_b128 per K-tile per block.
// 2-phase prefetch; XOR-swizzled LDS via pre-swizzled global source.
//   MODE 0: A=covC16, W=W_ih; writes M16; cell with c0=0, g=a*acc+bias.
//   MODE 1: A=h_{t-1},  W=W_hh; reads M16;  g=acc+a*M+bias.
// ---------------------------------------------------------------------------
template <int MODE>
__global__ __launch_bounds__(256, 2) void fused_step(
    const _Float16* __restrict__ A, int lda, const _Float16* __restrict__ W,
    const float* __restrict__ covT, int t, _Float16* __restrict__ M16,
    const float* __restrict__ b_ih, const float* __restrict__ b_hh,
    float* __restrict__ cbuf, _Float16* __restrict__ hout)  // h16 + t*HH
{
  __shared__ __align__(16) char smem[49152];
  _Float16* As0 = (_Float16*)smem;             // 64x64 f16, 8 KB
  _Float16* Bs0 = (_Float16*)(smem + 8192);    // 128x64 f16, 16 KB
  _Float16* As1 = (_Float16*)(smem + 24576);
  _Float16* Bs1 = (_Float16*)(smem + 32768);
  float* gls = (float*)smem;  // epilogue overlay: [4][64][33] f32, 33 KB

  const int tid = threadIdx.x;
  const int wave = tid >> 6, lane = tid & 63;
  const int r31 = lane & 31;       // fragment row/col within 32
  const int lhi32 = lane >> 5;     // k-half selector
  const int rowBase = blockIdx.y * 64;   // batch rows
  const int jBase = blockIdx.x * 32;     // j-tile (32 hidden cols)
  const int sRow = tid >> 3;             // 0..31 staging row
  const int sColSw = (((tid & 7) ^ (sRow & 7)) * 8);  // pre-swizzled k-chunk
  const int ldsOff = (tid & ~63) * 8;    // wave-uniform gload dest offset

  f32x16 acc0 = {};  // rows 0-31 of wave's 64-row strip
  f32x16 acc1 = {};  // rows 32-63

  // ---- staging: A 2 rounds, B 4 gate strips (rows g*HH + jBase + sRow) ----
#define STAGE(as, bs, kt)                                                     \
  {                                                                           \
    const int k0 = (kt)*64;                                                   \
    gload16(&A[(size_t)(rowBase + sRow) * lda + k0 + sColSw], (as) + ldsOff); \
    gload16(&A[(size_t)(rowBase + 32 + sRow) * lda + k0 + sColSw],            \
            (as) + 2048 + ldsOff);                                            \
    gload16(&W[(size_t)(0 * HH + jBase + sRow) * DD + k0 + sColSw],           \
            (bs) + 0 + ldsOff);                                               \
    gload16(&W[(size_t)(1 * HH + jBase + sRow) * DD + k0 + sColSw],           \
            (bs) + 2048 + ldsOff);                                            \
    gload16(&W[(size_t)(2 * HH + jBase + sRow) * DD + k0 + sColSw],           \
            (bs) + 4096 + ldsOff);                                            \
    gload16(&W[(size_t)(3 * HH + jBase + sRow) * DD + k0 + sColSw],           \
            (bs) + 6144 + ldsOff);                                            \
  }

  // ---- compute one K-tile (4 x k16) from LDS, swizzled reads ----
  // A frag: row = m*32 + r31, k = ks*16 + lhi32*8 (+e); chunk = ks*2+lhi32,
  // read at chunk ^ (row&7) = chunk ^ (lane&7)  [(32+r)&7 == r&7].
#define COMPUTE(as, bs)                                                       \
  {                                                                           \
    _Pragma("unroll") for (int ks = 0; ks < 4; ++ks) {                        \
      const int akx = (((ks * 2 + lhi32) ^ (lane & 7)) * 8);                  \
      const f16x8 a0 = *(const f16x8*)&(as)[r31 * 64 + akx];                  \
      const f16x8 a1 = *(const f16x8*)&(as)[(32 + r31) * 64 + akx];           \
      const f16x8 bf = *(const f16x8*)&(bs)[(wave * 32 + r31) * 64 + akx];    \
      acc0 = __builtin_amdgcn_mfma_f32_32x32x16_f16(a0, bf, acc0, 0, 0, 0);   \
      acc1 = __builtin_amdgcn_mfma_f32_32x32x16_f16(a1, bf, acc1, 0, 0, 0);   \
    }                                                                         \
  }

  STAGE(As0, Bs0, 0);
  __syncthreads();
  for (int kt = 0; kt < 16; kt += 2) {
    STAGE(As1, Bs1, kt + 1);   // prefetch next (in flight during compute)
    COMPUTE(As0, Bs0);
    __syncthreads();           // drains prefetch + guards As0 reuse
    if (kt + 2 < 16) STAGE(As0, Bs0, kt + 2);
    COMPUTE(As1, Bs1);
    __syncthreads();
  }

  // ---- epilogue: gate exchange through LDS (wave = gate) ----
  // C/D layout (m74/m101): col = lane&31, row = (reg&3)+8*(reg>>2)+4*(lane>>5)
#pragma unroll
  for (int reg = 0; reg < 16; ++reg) {
    const int grow = (reg & 3) + 8 * (reg >> 2) + 4 * lhi32;
    gls[(wave * 64 + grow) * 33 + r31] = acc0[reg];
    gls[(wave * 64 + 32 + grow) * 33 + r31] = acc1[reg];
  }
  __syncthreads();

  // thread owns jj = tid&31 (fixed), rows k*8 + (tid>>5), k=0..7
  const int jj = tid & 31;
  const int j = jBase + jj;
  float bia[4];
#pragma unroll
  for (int g = 0; g < 4; ++g) bia[g] = b_ih[g * HH + j] + b_hh[g * HH + j];

#pragma unroll
  for (int k = 0; k < 8; ++k) {
    const int row = k * 8 + (tid >> 5);
    const int b = rowBase + row;
    const float a = covT[b * TS + t];
    float pre[4];
#pragma unroll
    for (int g = 0; g < 4; ++g) {
      const float gv = gls[(g * 64 + row) * 33 + jj];
      if (MODE == 0) {
        M16[(size_t)b * NG + g * HH + j] = (_Float16)gv;
        pre[g] = a * gv + bia[g];
      } else {
        pre[g] = gv + a * (float)M16[(size_t)b * NG + g * HH + j] + bia[g];
      }
    }
    const float i_ = sigm_(pre[0]), f_ = sigm_(pre[1]);
    const float g_ = tanh_(pre[2]), o_ = sigm_(pre[3]);
    const float c_ =
        (MODE == 1 ? f_ * cbuf[(size_t)b * HH + j] : 0.f) + i_ * g_;
    cbuf[(size_t)b * HH + j] = c_;
    hout[(size_t)b * TS * HH + j] = (_Float16)(o_ * tanh_(c_));
  }
#undef STAGE
#undef COMPUTE
}

// ---------------------------------------------------------------------------
// Kernel D: softmax over t + temporal attention, reading fp16 h_all.
// ---------------------------------------------------------------------------
__global__ __launch_bounds__(256) void finale(
    const _Float16* __restrict__ h16, const float* __restrict__ attn_W,
    const float* __restrict__ attn_b, float* __restrict__ out) {
  const int b = blockIdx.x, tid = threadIdx.x;
  const f16x4* hb = (const f16x4*)(h16 + (size_t)b * TS * HH);
  float v[TS][4];
#pragma unroll
  for (int t = 0; t < TS; t++) {
    f16x4 hv = hb[t * 256 + tid];
#pragma unroll
    for (int q = 0; q < 4; q++) v[t][q] = (float)hv[q];
  }
  const float4 aw = ((const float4*)attn_W)[tid];
  const float awa[4] = {aw.x, aw.y, aw.z, aw.w};

  float4 outv[TS];
#pragma unroll
  for (int q = 0; q < 4; q++) {
    float m = -1e30f;
#pragma unroll
    for (int t = 0; t < TS; t++) m = fmaxf(m, v[t][q]);
    float e[TS], s = 0.f;
#pragma unroll
    for (int t = 0; t < TS; t++) {
      e[t] = __expf(v[t][q] - m);
      s += e[t];
    }
    const float inv = 1.f / s;
#pragma unroll
    for (int t = 0; t < TS; t++) ((float*)&outv[t])[q] = e[t] * inv;
  }
#pragma unroll
  for (int t = 0; t < TS; t++)
    ((float4*)out)[(size_t)b * TS * 256 + t * 256 + tid] = outv[t];

  float pt[TS];
#pragma unroll
  for (int t = 0; t < TS; t++) {
    pt[t] = tanh_(v[t][0]) * awa[0] + tanh_(v[t][1]) * awa[1] +
            tanh_(v[t][2]) * awa[2] + tanh_(v[t][3]) * awa[3];
  }
#pragma unroll
  for (int t = 0; t < TS; t++)
    for (int m = 32; m >= 1; m >>= 1) pt[t] += __shfl_xor(pt[t], m);
  __shared__ float red[4][TS];
  const int wave = tid >> 6, lane = tid & 63;
  if (lane == 0) {
#pragma unroll
    for (int t = 0; t < TS; t++) red[wave][t] = pt[t];
  }
  __syncthreads();
  if (tid < TS) {
    float s = red[0][tid] + red[1][tid] + red[2][tid] + red[3][tid];
    out[(size_t)BSZ * TS * HH + b * TS + tid] = sigm_(s + attn_b[0]);
  }
}

// ---------------------------------------------------------------------------
extern "C" void kernel_launch(void* const* d_in, const int* in_sizes, int n_in,
                              void* d_out, int out_size, void* d_ws,
                              size_t ws_size, hipStream_t stream) {
  const float* x = (const float*)d_in[0];
  const float* xsh = (const float*)d_in[1];
  const float* W_ih = (const float*)d_in[2];
  const float* W_hh = (const float*)d_in[3];
  const float* b_ih = (const float*)d_in[4];
  const float* b_hh = (const float*)d_in[5];
  const float* attn_W = (const float*)d_in[6];
  const float* attn_b = (const float*)d_in[7];
  float* out = (float*)d_out;
  float* w = (float*)d_ws;

  // workspace (fp32 words), total ~42 MB, no aliasing
  float* covT = w;                      // 8192
  _Float16* covC16 = (_Float16*)(w + 8192);        // 1M f16 (0.5M words)
  _Float16* Wih16 = (_Float16*)(w + 532480);       // 4M f16 (2M words)
  _Float16* Whh16 = (_Float16*)(w + 2629632);      // 4M f16 (2M words)
  _Float16* M16 = (_Float16*)(w + 4726784);        // 4M f16 (2M words)
  float* cbuf = w + 6823936;                       // 1M words fp32
  _Float16* h16 = (_Float16*)(w + 7872512);        // 7M f16 (3.5M words)

  conv_w<<<1024, 256, 0, stream>>>(W_ih, W_hh, Wih16, Whh16);
  cov_kernel<<<dim3(BSZ), dim3(256), 0, stream>>>(x, xsh, covT, covC16);

  // t = 0: M = covC @ W_ih^T fused with first cell (c0 = 0)
  fused_step<0><<<dim3(32, 16), dim3(256), 0, stream>>>(
      covC16, DD, Wih16, covT, 0, M16, b_ih, b_hh, cbuf, h16);
  for (int t = 1; t < TS; t++) {
    fused_step<1><<<dim3(32, 16), dim3(256), 0, stream>>>(
        h16 + (size_t)(t - 1) * HH, TS * HH, Whh16, covT, t, M16, b_ih, b_hh,
        cbuf, h16 + (size_t)t * HH);
  }
  finale<<<dim3(BSZ), dim3(256), 0, stream>>>(h16, attn_W, attn_b, out);
}